// Round 14
// baseline (246.803 us; speedup 1.0000x reference)
//
#include <hip/hip_runtime.h>
#include <hip/hip_bf16.h>

typedef __attribute__((ext_vector_type(8))) short bf16x8;
typedef __attribute__((ext_vector_type(4))) float f32x4;
typedef __attribute__((ext_vector_type(4))) unsigned short u16x4;

__device__ __forceinline__ unsigned short f2bf(float f) {
    __hip_bfloat16 h = __float2bfloat16(f);   // RTNE; pairs fuse to v_cvt_pk_bf16_f32
    union { __hip_bfloat16 h; unsigned short u; } v; v.h = h;
    return v.u;
}

__device__ __forceinline__ void cp16_g2l(const void* g, void* l) {
    __builtin_amdgcn_global_load_lds(
        (const __attribute__((address_space(1))) unsigned int*)g,
        (__attribute__((address_space(3))) unsigned int*)l, 16, 0, 0);
}

// ---- one-time: W_h f32 [128][384] -> plain bf16 row-major image in ws ----
__global__ __launch_bounds__(384) void k_cvtW(const float* __restrict__ Wh,
                                              unsigned short* __restrict__ Wbf) {
    int n = blockIdx.x, k = threadIdx.x;
    Wbf[n * 384 + k] = f2bf(Wh[n * 384 + k]);
}

// Block tile: 64 own rows x 128 cols, FOUR waves (wave = 32 N-cols x 64 i-rows).
// 0.5 ds_read per MFMA: per K-step a wave reads af[4] once and feeds TWO W
// fragments (wreg[2], 96 VGPR pinned) -> halves LDS-pipe traffic vs the 8-wave
// 16-col layout (which was the most-loaded pipe). (256,3): 3 blocks/CU
// (LDS 52KiB x3 = 156 <= 160), 12 waves/CU.
// TRANSPOSED COMPUTE: mfma(W_frag, emb_frag) -> D[n][i]; thread owns 4
// consecutive columns -> 8B result writes. Counted-vmcnt pipeline: cO loads
// issued BEFORE the phase barrier so DMA(8)+stores(8)+loads(2) drain as vmcnt(10).
template<int LEAF, int LAST>
__global__ __launch_bounds__(256, 3) void k_level(
    const unsigned short* __restrict__ embIn,
    const float* __restrict__ contO,   // [n][8] own contents
    const float* __restrict__ contC,   // [2n][8] child contents (LEAF only)
    const unsigned short* __restrict__ Wbf, // bf16 W image [128*384]
    const float* __restrict__ Wu,      // [128][8]
    const float* __restrict__ bu,      // [128]
    const float* __restrict__ bh,      // [128]
    unsigned short* __restrict__ embOut, // child-image layout
    float* __restrict__ outF,          // row-major f32 (LAST)
    int n_nodes)
{
    // LDS: 32K (A) + 16K (u) + 4K (wu) = 52 KiB
    __shared__ __align__(16) unsigned short A_lds[2][64][128]; // [cc][il][n^swz]
    __shared__ __align__(16) unsigned short u_lds[64][128];    // [i][n^swz]
    __shared__ __align__(16) unsigned short wu_lds[8][32][8];  // [nf][l4*16+l15][e]

    const int t = threadIdx.x, lane = t & 63, wid = t >> 6;    // 4 waves
    const int l15 = lane & 15, l4 = lane >> 4;

    // ---- persistent W fragments: wave's 32-col slice (96 VGPR, pinned) ----
    // lane (l4,l15) holds W[n = wid*32 + nf2*16 + l15][k = kb*32 + l4*8 + e]
    bf16x8 wreg[2][12];
    #pragma unroll
    for (int nf2 = 0; nf2 < 2; ++nf2) {
        int n = wid * 32 + nf2 * 16 + l15;
        #pragma unroll
        for (int kb = 0; kb < 12; ++kb)
            wreg[nf2][kb] = *reinterpret_cast<const bf16x8*>(Wbf + n * 384 + kb * 32 + l4 * 8);
    }
    #pragma unroll
    for (int kb = 0; kb < 12; ++kb)
        asm volatile("" : "+v"(wreg[0][kb]), "+v"(wreg[1][kb]));

    // ---- Wu/bu fragment table (A-operand of the u-GEMM), wave 0 writes ----
    if (wid == 0 && l4 < 2) {
        #pragma unroll
        for (int nf = 0; nf < 8; ++nf) {
            int n = nf * 16 + l15;
            bf16x8 v = {0, 0, 0, 0, 0, 0, 0, 0};
            if (l4 == 0) {
                #pragma unroll
                for (int k = 0; k < 8; ++k) ((unsigned short*)&v)[k] = f2bf(Wu[n * 8 + k]);
            } else {
                ((unsigned short*)&v)[0] = f2bf(bu[n]);   // bias column (k=8)
            }
            *(bf16x8*)&wu_lds[nf][l4 * 16 + l15][0] = v;
        }
    }
    // bias for D[n][i]: n = wid*32 + nf2*16 + l4*4 + r
    f32x4 bh4[2];
    #pragma unroll
    for (int nf2 = 0; nf2 < 2; ++nf2)
        bh4[nf2] = *(const f32x4*)&bh[wid * 32 + nf2 * 16 + l4 * 4];

    bf16x8 zeroA = {0, 0, 0, 0, 0, 0, 0, 0};
    bf16x8 onesA = zeroA; ((unsigned short*)&onesA)[0] = 0x3F80;  // 1.0 at k=8

    const int ntiles = n_nodes >> 6;
    const int stride = gridDim.x;
    const int tile0 = blockIdx.x;
    if (tile0 >= ntiles) return;

    f32x4 cO0 = {0,0,0,0}, cO1 = {0,0,0,0};

    // ---- prologue: tile0 A DMA (8/thread) + own contents ----
    if (!LEAF) {
        const unsigned short* src = embIn + (size_t)tile0 * 16384;
        #pragma unroll
        for (int it = 0; it < 8; ++it) {
            int q = t + it * 256;
            cp16_g2l(src + q * 8, &A_lds[0][0][0] + q * 8);
        }
    }
    if (l4 == 0) {
        const float* p = contO + ((size_t)tile0 * 64 + wid * 16 + l15) * 8;
        cO0 = *(const f32x4*)p; cO1 = *(const f32x4*)(p + 4);
    }
    __syncthreads();  // drains prologue DMA/loads; wu_lds visible

    for (int tile = tile0; tile < ntiles; tile += stride) {
        const int tnext = tile + stride;

        // ======== u-phase: D[n][i], i = wid*16+l15, all 128 n (8 MFMA) ========
        {
            bf16x8 cb = zeroA;                 // B-operand: cont^T
            if (l4 == 0) {
                #pragma unroll
                for (int e = 0; e < 4; ++e) {
                    ((unsigned short*)&cb)[e]     = f2bf(cO0[e]);
                    ((unsigned short*)&cb)[e + 4] = f2bf(cO1[e]);
                }
            } else if (l4 == 1) cb = onesA;
            const int i = wid * 16 + l15;
            #pragma unroll
            for (int nf = 0; nf < 8; ++nf) {
                bf16x8 wv = zeroA;
                if (l4 < 2) wv = *(const bf16x8*)&wu_lds[nf][l4 * 16 + l15][0];
                f32x4 z = {0.f, 0.f, 0.f, 0.f};
                z = __builtin_amdgcn_mfma_f32_16x16x32_bf16(wv, cb, z, 0, 0, 0);
                u16x4 pk;
                #pragma unroll
                for (int r = 0; r < 4; ++r) pk[r] = f2bf(fmaxf(z[r], 0.f));
                int n4 = nf * 16 + l4 * 4;
                *(u16x4*)&u_lds[i][n4 ^ ((i & 7) << 3)] = pk;
            }
        }
        if (LEAF) {  // child-u: child rows wid*32..+32, all 128 n (16 MFMA)
            const float* pcBase = contC + ((size_t)tile * 128 + wid * 32 + l15) * 8;
            #pragma unroll
            for (int rb = 0; rb < 2; ++rb) {
                bf16x8 cb = zeroA;
                if (l4 == 0) {
                    f32x4 a  = *(const f32x4*)(pcBase + rb * 128);
                    f32x4 b2 = *(const f32x4*)(pcBase + rb * 128 + 4);
                    #pragma unroll
                    for (int e = 0; e < 4; ++e) {
                        ((unsigned short*)&cb)[e]     = f2bf(a[e]);
                        ((unsigned short*)&cb)[e + 4] = f2bf(b2[e]);
                    }
                } else if (l4 == 1) cb = onesA;
                const int rr = wid * 32 + rb * 16 + l15;   // local child row
                const int cc = rr & 1, il = rr >> 1;
                #pragma unroll
                for (int nf = 0; nf < 8; ++nf) {
                    bf16x8 wv = zeroA;
                    if (l4 < 2) wv = *(const bf16x8*)&wu_lds[nf][l4 * 16 + l15][0];
                    f32x4 z = {0.f, 0.f, 0.f, 0.f};
                    z = __builtin_amdgcn_mfma_f32_16x16x32_bf16(wv, cb, z, 0, 0, 0);
                    u16x4 pk;
                    #pragma unroll
                    for (int r = 0; r < 4; ++r) pk[r] = f2bf(fmaxf(z[r], 0.f));
                    int n4 = nf * 16 + l4 * 4;
                    *(u16x4*)&A_lds[cc][il][n4 ^ ((il & 7) << 3)] = pk;
                }
            }
        }

        // ---- prefetch next tile's own contents (always issued, clamped) ----
        {
            int tn = (tnext < ntiles) ? tnext : tile;
            if (l4 == 0) {
                const float* p = contO + ((size_t)tn * 64 + wid * 16 + l15) * 8;
                cO0 = *(const f32x4*)p; cO1 = *(const f32x4*)(p + 4);
            }
        }

        // ======== phase barrier: A ready (counted vmcnt), u/A LDS visible ========
        if (!LEAF) asm volatile("s_waitcnt vmcnt(10)" ::: "memory");  // drain 8 DMA; leave 8 stores + 2 loads
        asm volatile("s_waitcnt lgkmcnt(0)" ::: "memory");
        __builtin_amdgcn_sched_barrier(0);
        __builtin_amdgcn_s_barrier();
        __builtin_amdgcn_sched_barrier(0);

        // ======== main GEMM: D[n][i], n = wid*32+nf2*16+l4*4+r, i = mf*16+l15 ========
        f32x4 acc[2][4];
        #pragma unroll
        for (int nf2 = 0; nf2 < 2; ++nf2)
            #pragma unroll
            for (int mf = 0; mf < 4; ++mf) acc[nf2][mf] = bh4[nf2];

        #pragma unroll
        for (int kb = 0; kb < 8; ++kb) {   // A slabs: 4 reads feed 8 MFMAs
            bf16x8 af[4];
            #pragma unroll
            for (int mf = 0; mf < 4; ++mf) {
                int i = mf * 16 + l15;
                af[mf] = *(const bf16x8*)&A_lds[kb >> 2][i][((((kb & 3) * 4) + l4) ^ (i & 7)) * 8];
            }
            #pragma unroll
            for (int mf = 0; mf < 4; ++mf) {
                acc[0][mf] = __builtin_amdgcn_mfma_f32_16x16x32_bf16(wreg[0][kb], af[mf], acc[0][mf], 0, 0, 0);
                acc[1][mf] = __builtin_amdgcn_mfma_f32_16x16x32_bf16(wreg[1][kb], af[mf], acc[1][mf], 0, 0, 0);
            }
        }

        // A consumed -> barrier, then prefetch next tile's A DMA
        if (!LEAF) {
            asm volatile("s_waitcnt lgkmcnt(0)" ::: "memory");
            __builtin_amdgcn_sched_barrier(0);
            __builtin_amdgcn_s_barrier();
            __builtin_amdgcn_sched_barrier(0);
            if (tnext < ntiles) {
                const unsigned short* src = embIn + (size_t)tnext * 16384;
                #pragma unroll
                for (int it = 0; it < 8; ++it) {
                    int q = t + it * 256;
                    cp16_g2l(src + q * 8, &A_lds[0][0][0] + q * 8);
                }
            }
        }

        #pragma unroll
        for (int kb = 8; kb < 12; ++kb) {  // u
            bf16x8 af[4];
            #pragma unroll
            for (int mf = 0; mf < 4; ++mf) {
                int i = mf * 16 + l15;
                af[mf] = *(const bf16x8*)&u_lds[i][((((kb - 8) * 4) + l4) ^ (i & 7)) * 8];
            }
            #pragma unroll
            for (int mf = 0; mf < 4; ++mf) {
                acc[0][mf] = __builtin_amdgcn_mfma_f32_16x16x32_bf16(wreg[0][kb], af[mf], acc[0][mf], 0, 0, 0);
                acc[1][mf] = __builtin_amdgcn_mfma_f32_16x16x32_bf16(wreg[1][kb], af[mf], acc[1][mf], 0, 0, 0);
            }
        }

        // ======== epilogue: 8 direct 8B/16B stores per thread ========
        if (LAST) {
            #pragma unroll
            for (int nf2 = 0; nf2 < 2; ++nf2)
                #pragma unroll
                for (int mf = 0; mf < 4; ++mf) {
                    int i = mf * 16 + l15;
                    f32x4 o;
                    #pragma unroll
                    for (int r = 0; r < 4; ++r) o[r] = fmaxf(acc[nf2][mf][r], 0.f);
                    *(f32x4*)&outF[(size_t)(tile * 64 + i) * 128 + wid * 32 + nf2 * 16 + l4 * 4] = o;
                }
        } else {
            #pragma unroll
            for (int nf2 = 0; nf2 < 2; ++nf2)
                #pragma unroll
                for (int mf = 0; mf < 4; ++mf) {
                    int i = mf * 16 + l15;
                    int Rg = tile * 64 + i;
                    int rr = Rg & 127, cc = rr & 1, il = rr >> 1;
                    u16x4 pk;
                    #pragma unroll
                    for (int r = 0; r < 4; ++r) pk[r] = f2bf(fmaxf(acc[nf2][mf][r], 0.f));
                    int n4 = wid * 32 + nf2 * 16 + l4 * 4;
                    *(u16x4*)&embOut[(size_t)(Rg >> 7) * 16384 + cc * 8192 + il * 128
                                     + (n4 ^ ((il & 7) << 3))] = pk;
                }
        }

        // ======== post barrier: all LDS reads done before next tile's writes ========
        asm volatile("s_waitcnt lgkmcnt(0)" ::: "memory");
        __builtin_amdgcn_sched_barrier(0);
        __builtin_amdgcn_s_barrier();
    }
}

extern "C" void kernel_launch(void* const* d_in, const int* in_sizes, int n_in,
                              void* d_out, int out_size, void* d_ws, size_t ws_size,
                              hipStream_t stream) {
    const float* contents[10];
    for (int j = 0; j < 10; ++j) contents[j] = (const float*)d_in[j];
    const float* Wu = (const float*)d_in[19];
    const float* bu = (const float*)d_in[20];
    const float* Wh = (const float*)d_in[21];
    const float* bh = (const float*)d_in[22];

    unsigned short* Wbf  = (unsigned short*)d_ws;                                     // 96 KiB
    unsigned short* bufE = (unsigned short*)((char*)d_ws + (1u << 20));               // 64 MiB (even-level embs)
    unsigned short* bufO = (unsigned short*)((char*)d_ws + (1u << 20) + (64u << 20)); // 32 MiB (odd-level embs)

    k_cvtW<<<128, 384, 0, stream>>>(Wh, Wbf);

    // level 8 (leaf-fused): children = relu(contents_9 @ Wu^T + bu) computed in-kernel
    {
        int ntiles = (1024 << 8) >> 6;   // 4096
        int grid = ntiles < 768 ? ntiles : 768;
        k_level<1, 0><<<grid, 256, 0, stream>>>(nullptr, contents[8], contents[9], Wbf,
                                                Wu, bu, bh, bufE, nullptr, 1024 << 8);
    }
    // levels 7..1
    for (int j = 7; j >= 1; --j) {
        int n = 1024 << j;
        const unsigned short* in = (j & 1) ? bufE : bufO;  // emb_{j+1}
        unsigned short* outp     = (j & 1) ? bufO : bufE;  // emb_j
        int ntiles = n >> 6;
        int grid = ntiles < 768 ? ntiles : 768;
        k_level<0, 0><<<grid, 256, 0, stream>>>(in, contents[j], nullptr, Wbf,
                                                Wu, bu, bh, outp, nullptr, n);
    }
    // level 0 -> f32 output (16 tiles)
    k_level<0, 1><<<16, 256, 0, stream>>>(bufO, contents[0], nullptr, Wbf,
                                          Wu, bu, bh, nullptr, (float*)d_out, 1024);
}

// Round 15
// 167.781 us; speedup vs baseline: 1.4710x; 1.4710x over previous
//
#include <hip/hip_runtime.h>
#include <hip/hip_bf16.h>

typedef __attribute__((ext_vector_type(8))) short bf16x8;
typedef __attribute__((ext_vector_type(4))) float f32x4;
typedef __attribute__((ext_vector_type(4))) unsigned short u16x4;

__device__ __forceinline__ unsigned short f2bf(float f) {
    __hip_bfloat16 h = __float2bfloat16(f);   // RTNE; pairs fuse to v_cvt_pk_bf16_f32
    union { __hip_bfloat16 h; unsigned short u; } v; v.h = h;
    return v.u;
}

__device__ __forceinline__ void cp16_g2l(const void* g, void* l) {
    __builtin_amdgcn_global_load_lds(
        (const __attribute__((address_space(1))) unsigned int*)g,
        (__attribute__((address_space(3))) unsigned int*)l, 16, 0, 0);
}

// ---- one-time: W_h f32 [128][384] -> plain bf16 row-major image in ws ----
__global__ __launch_bounds__(384) void k_cvtW(const float* __restrict__ Wh,
                                              unsigned short* __restrict__ Wbf) {
    int n = blockIdx.x, k = threadIdx.x;
    Wbf[n * 384 + k] = f2bf(Wh[n * 384 + k]);
}

// Block tile: 64 own rows x 128 cols, 8 waves (wave = 64 rows x 16-col slice).
// TRANSPOSED COMPUTE: mfma(W_frag, emb_frag) -> D[n][i]; thread owns 4
// consecutive columns -> all result writes are 8B chunks.
// FULL-WIDTH XOR SWIZZLE (i&15, 16 slots): the old (i&7) swizzle confined all
// 64 lanes to the lower 8 slots for kb&3<2 -> 8-way bank conflict; 16-slot
// spread gives the structural 4-way floor for wave64 ds_read_b128.
// Applied uniformly: phys_elem = logical_elem ^ ((row&15)<<3) on u_lds, A_lds
// (leaf writes + GEMM reads) and the global child-image; DMA copies linearly.
template<int LEAF, int LAST>
__global__ __launch_bounds__(512, 4) void k_level(
    const unsigned short* __restrict__ embIn,
    const float* __restrict__ contO,   // [n][8] own contents
    const float* __restrict__ contC,   // [2n][8] child contents (LEAF only)
    const unsigned short* __restrict__ Wbf, // bf16 W image [128*384]
    const float* __restrict__ Wu,      // [128][8]
    const float* __restrict__ bu,      // [128]
    const float* __restrict__ bh,      // [128]
    unsigned short* __restrict__ embOut, // child-image layout
    float* __restrict__ outF,          // row-major f32 (LAST)
    int n_nodes)
{
    // LDS: 32K (A) + 16K (u) + 4K (wu) = 52 KiB -> 2 blocks/CU (16 waves)
    __shared__ __align__(16) unsigned short A_lds[2][64][128]; // [cc][il][n^swz16]
    __shared__ __align__(16) unsigned short u_lds[64][128];    // [i][n^swz16]
    __shared__ __align__(16) unsigned short wu_lds[8][32][8];  // [nf][l4*16+l15][e]

    const int t = threadIdx.x, lane = t & 63, wid = t >> 6;    // 8 waves
    const int l15 = lane & 15, l4 = lane >> 4;
    const int wrow = wid & 3;        // u-phase row quarter
    const int wcolh = wid >> 2;      // u-phase col half

    // ---- persistent W fragments: wave's 16-col slice (48 VGPR, pinned) ----
    bf16x8 wreg[12];
    {
        int n = wid * 16 + l15;
        #pragma unroll
        for (int kb = 0; kb < 12; ++kb)
            wreg[kb] = *reinterpret_cast<const bf16x8*>(Wbf + n * 384 + kb * 32 + l4 * 8);
    }
    #pragma unroll
    for (int kb = 0; kb < 12; ++kb)
        asm volatile("" : "+v"(wreg[kb]));

    // ---- Wu/bu fragment table (A-operand of the u-GEMM) ----
    if (wid == 0 && l4 < 2) {
        #pragma unroll
        for (int nf = 0; nf < 8; ++nf) {
            int n = nf * 16 + l15;
            bf16x8 v = {0, 0, 0, 0, 0, 0, 0, 0};
            if (l4 == 0) {
                #pragma unroll
                for (int k = 0; k < 8; ++k) ((unsigned short*)&v)[k] = f2bf(Wu[n * 8 + k]);
            } else {
                ((unsigned short*)&v)[0] = f2bf(bu[n]);   // bias column (k=8)
            }
            *(bf16x8*)&wu_lds[nf][l4 * 16 + l15][0] = v;
        }
    }
    // bias for D[n][i]: n = wid*16 + l4*4 + r
    const f32x4 bh4 = *(const f32x4*)&bh[wid * 16 + l4 * 4];

    bf16x8 zeroA = {0, 0, 0, 0, 0, 0, 0, 0};
    bf16x8 onesA = zeroA; ((unsigned short*)&onesA)[0] = 0x3F80;  // 1.0 at k=8

    const int ntiles = n_nodes >> 6;
    const int stride = gridDim.x;
    const int tile0 = blockIdx.x;
    if (tile0 >= ntiles) return;

    f32x4 cO0 = {0,0,0,0}, cO1 = {0,0,0,0};

    // ---- prologue: tile0 A DMA + own contents ----
    if (!LEAF) {
        const unsigned short* src = embIn + (size_t)tile0 * 16384;
        #pragma unroll
        for (int it = 0; it < 4; ++it) {
            int q = t + it * 512;
            cp16_g2l(src + q * 8, &A_lds[0][0][0] + q * 8);
        }
    }
    if (l4 == 0) {
        const float* p = contO + ((size_t)tile0 * 64 + wrow * 16 + l15) * 8;
        cO0 = *(const f32x4*)p; cO1 = *(const f32x4*)(p + 4);
    }
    __syncthreads();  // drains prologue DMA/loads; wu_lds visible

    for (int tile = tile0; tile < ntiles; tile += stride) {
        const int tnext = tile + stride;

        // ======== u-phase: D[n][i], i = wrow*16+l15, n in wcolh half ========
        {
            bf16x8 cb = zeroA;                 // B-operand: cont^T
            if (l4 == 0) {
                #pragma unroll
                for (int e = 0; e < 4; ++e) {
                    ((unsigned short*)&cb)[e]     = f2bf(cO0[e]);
                    ((unsigned short*)&cb)[e + 4] = f2bf(cO1[e]);
                }
            } else if (l4 == 1) cb = onesA;
            const int i = wrow * 16 + l15;
            #pragma unroll
            for (int nfi = 0; nfi < 4; ++nfi) {
                int nf = wcolh * 4 + nfi;
                bf16x8 wv = zeroA;
                if (l4 < 2) wv = *(const bf16x8*)&wu_lds[nf][l4 * 16 + l15][0];
                f32x4 z = {0.f, 0.f, 0.f, 0.f};
                z = __builtin_amdgcn_mfma_f32_16x16x32_bf16(wv, cb, z, 0, 0, 0);
                u16x4 pk;
                #pragma unroll
                for (int r = 0; r < 4; ++r) pk[r] = f2bf(fmaxf(z[r], 0.f));
                int n4 = nf * 16 + l4 * 4;
                *(u16x4*)&u_lds[i][n4 ^ ((i & 15) << 3)] = pk;
            }
        }
        if (LEAF) {  // child-u: D[n][child], child = wrow*32 + rb*16 + l15
            const float* pcBase = contC + ((size_t)tile * 128 + wrow * 32 + l15) * 8;
            #pragma unroll
            for (int rb = 0; rb < 2; ++rb) {
                bf16x8 cb = zeroA;
                if (l4 == 0) {
                    f32x4 a  = *(const f32x4*)(pcBase + rb * 128);
                    f32x4 b2 = *(const f32x4*)(pcBase + rb * 128 + 4);
                    #pragma unroll
                    for (int e = 0; e < 4; ++e) {
                        ((unsigned short*)&cb)[e]     = f2bf(a[e]);
                        ((unsigned short*)&cb)[e + 4] = f2bf(b2[e]);
                    }
                } else if (l4 == 1) cb = onesA;
                const int rr = wrow * 32 + rb * 16 + l15;   // local child row
                const int cc = rr & 1, il = rr >> 1;
                #pragma unroll
                for (int nfi = 0; nfi < 4; ++nfi) {
                    int nf = wcolh * 4 + nfi;
                    bf16x8 wv = zeroA;
                    if (l4 < 2) wv = *(const bf16x8*)&wu_lds[nf][l4 * 16 + l15][0];
                    f32x4 z = {0.f, 0.f, 0.f, 0.f};
                    z = __builtin_amdgcn_mfma_f32_16x16x32_bf16(wv, cb, z, 0, 0, 0);
                    u16x4 pk;
                    #pragma unroll
                    for (int r = 0; r < 4; ++r) pk[r] = f2bf(fmaxf(z[r], 0.f));
                    int n4 = nf * 16 + l4 * 4;
                    *(u16x4*)&A_lds[cc][il][n4 ^ ((il & 15) << 3)] = pk;
                }
            }
        }

        // ---- prefetch next tile's own contents (always issued, clamped) ----
        {
            int tn = (tnext < ntiles) ? tnext : tile;
            if (l4 == 0) {
                const float* p = contO + ((size_t)tn * 64 + wrow * 16 + l15) * 8;
                cO0 = *(const f32x4*)p; cO1 = *(const f32x4*)(p + 4);
            }
        }

        // ======== phase barrier: A ready (counted vmcnt), u/A LDS visible ========
        if (!LEAF) asm volatile("s_waitcnt vmcnt(6)" ::: "memory");  // drain 4 DMA; leave 4 stores + 2 loads
        asm volatile("s_waitcnt lgkmcnt(0)" ::: "memory");
        __builtin_amdgcn_sched_barrier(0);
        __builtin_amdgcn_s_barrier();
        __builtin_amdgcn_sched_barrier(0);

        // ======== main GEMM: acc = W·emb^T, D[n = wid*16+l4*4+r][i = mf*16+l15] ========
        f32x4 acc[4];
        #pragma unroll
        for (int mf = 0; mf < 4; ++mf) acc[mf] = bh4;

        #pragma unroll
        for (int kb = 0; kb < 8; ++kb) {   // A slabs (emb as B-operand)
            bf16x8 af[4];
            #pragma unroll
            for (int mf = 0; mf < 4; ++mf) {
                int i = mf * 16 + l15;
                af[mf] = *(const bf16x8*)&A_lds[kb >> 2][i][((((kb & 3) * 4) + l4) ^ (i & 15)) * 8];
            }
            #pragma unroll
            for (int mf = 0; mf < 4; ++mf)
                acc[mf] = __builtin_amdgcn_mfma_f32_16x16x32_bf16(wreg[kb], af[mf], acc[mf], 0, 0, 0);
        }

        // A consumed -> barrier, then prefetch next tile's A DMA
        if (!LEAF) {
            asm volatile("s_waitcnt lgkmcnt(0)" ::: "memory");
            __builtin_amdgcn_sched_barrier(0);
            __builtin_amdgcn_s_barrier();
            __builtin_amdgcn_sched_barrier(0);
            if (tnext < ntiles) {
                const unsigned short* src = embIn + (size_t)tnext * 16384;
                #pragma unroll
                for (int it = 0; it < 4; ++it) {
                    int q = t + it * 512;
                    cp16_g2l(src + q * 8, &A_lds[0][0][0] + q * 8);
                }
            }
        }

        #pragma unroll
        for (int kb = 8; kb < 12; ++kb) {  // u
            bf16x8 af[4];
            #pragma unroll
            for (int mf = 0; mf < 4; ++mf) {
                int i = mf * 16 + l15;
                af[mf] = *(const bf16x8*)&u_lds[i][((((kb - 8) * 4) + l4) ^ (i & 15)) * 8];
            }
            #pragma unroll
            for (int mf = 0; mf < 4; ++mf)
                acc[mf] = __builtin_amdgcn_mfma_f32_16x16x32_bf16(wreg[kb], af[mf], acc[mf], 0, 0, 0);
        }

        // ======== epilogue: direct 8B/16B stores (thread owns 4 consecutive cols) ========
        if (LAST) {
            #pragma unroll
            for (int mf = 0; mf < 4; ++mf) {
                int i = mf * 16 + l15;
                f32x4 o;
                #pragma unroll
                for (int r = 0; r < 4; ++r) o[r] = fmaxf(acc[mf][r], 0.f);
                *(f32x4*)&outF[(size_t)(tile * 64 + i) * 128 + wid * 16 + l4 * 4] = o;
            }
        } else {
            #pragma unroll
            for (int mf = 0; mf < 4; ++mf) {
                int i = mf * 16 + l15;
                int Rg = tile * 64 + i;
                int rr = Rg & 127, cc = rr & 1, il = rr >> 1;
                u16x4 pk;
                #pragma unroll
                for (int r = 0; r < 4; ++r) pk[r] = f2bf(fmaxf(acc[mf][r], 0.f));
                int n4 = wid * 16 + l4 * 4;
                *(u16x4*)&embOut[(size_t)(Rg >> 7) * 16384 + cc * 8192 + il * 128
                                 + (n4 ^ ((il & 15) << 3))] = pk;
            }
        }

        // ======== post barrier: all LDS reads done before next tile's writes ========
        asm volatile("s_waitcnt lgkmcnt(0)" ::: "memory");
        __builtin_amdgcn_sched_barrier(0);
        __builtin_amdgcn_s_barrier();
    }
}

extern "C" void kernel_launch(void* const* d_in, const int* in_sizes, int n_in,
                              void* d_out, int out_size, void* d_ws, size_t ws_size,
                              hipStream_t stream) {
    const float* contents[10];
    for (int j = 0; j < 10; ++j) contents[j] = (const float*)d_in[j];
    const float* Wu = (const float*)d_in[19];
    const float* bu = (const float*)d_in[20];
    const float* Wh = (const float*)d_in[21];
    const float* bh = (const float*)d_in[22];

    unsigned short* Wbf  = (unsigned short*)d_ws;                                     // 96 KiB
    unsigned short* bufE = (unsigned short*)((char*)d_ws + (1u << 20));               // 64 MiB (even-level embs)
    unsigned short* bufO = (unsigned short*)((char*)d_ws + (1u << 20) + (64u << 20)); // 32 MiB (odd-level embs)

    k_cvtW<<<128, 384, 0, stream>>>(Wh, Wbf);

    // level 8 (leaf-fused): children = relu(contents_9 @ Wu^T + bu) computed in-kernel
    {
        int ntiles = (1024 << 8) >> 6;   // 4096
        int grid = ntiles < 512 ? ntiles : 512;
        k_level<1, 0><<<grid, 512, 0, stream>>>(nullptr, contents[8], contents[9], Wbf,
                                                Wu, bu, bh, bufE, nullptr, 1024 << 8);
    }
    // levels 7..1
    for (int j = 7; j >= 1; --j) {
        int n = 1024 << j;
        const unsigned short* in = (j & 1) ? bufE : bufO;  // emb_{j+1}
        unsigned short* outp     = (j & 1) ? bufO : bufE;  // emb_j
        int ntiles = n >> 6;
        int grid = ntiles < 512 ? ntiles : 512;
        k_level<0, 0><<<grid, 512, 0, stream>>>(in, contents[j], nullptr, Wbf,
                                                Wu, bu, bh, outp, nullptr, n);
    }
    // level 0 -> f32 output (16 tiles)
    k_level<0, 1><<<16, 512, 0, stream>>>(bufO, contents[0], nullptr, Wbf,
                                          Wu, bu, bh, nullptr, (float*)d_out, 1024);
}

// Round 16
// 144.526 us; speedup vs baseline: 1.7077x; 1.1609x over previous
//
#include <hip/hip_runtime.h>
#include <hip/hip_bf16.h>

typedef __attribute__((ext_vector_type(8))) short bf16x8;
typedef __attribute__((ext_vector_type(4))) float f32x4;
typedef __attribute__((ext_vector_type(4))) unsigned short u16x4;

__device__ __forceinline__ unsigned short f2bf(float f) {
    __hip_bfloat16 h = __float2bfloat16(f);   // RTNE; pairs fuse to v_cvt_pk_bf16_f32
    union { __hip_bfloat16 h; unsigned short u; } v; v.h = h;
    return v.u;
}

__device__ __forceinline__ void cp16_g2l(const void* g, void* l) {
    __builtin_amdgcn_global_load_lds(
        (const __attribute__((address_space(1))) unsigned int*)g,
        (__attribute__((address_space(3))) unsigned int*)l, 16, 0, 0);
}

// ---- one-time: W_h f32 [128][384] -> plain bf16 row-major image in ws ----
__global__ __launch_bounds__(384) void k_cvtW(const float* __restrict__ Wh,
                                              unsigned short* __restrict__ Wbf) {
    int n = blockIdx.x, k = threadIdx.x;
    Wbf[n * 384 + k] = f2bf(Wh[n * 384 + k]);
}

// ================= big-level kernel (levels 8..6) — identical to round 15 ==========
template<int LEAF, int LAST>
__global__ __launch_bounds__(512, 4) void k_level(
    const unsigned short* __restrict__ embIn,
    const float* __restrict__ contO,
    const float* __restrict__ contC,
    const unsigned short* __restrict__ Wbf,
    const float* __restrict__ Wu,
    const float* __restrict__ bu,
    const float* __restrict__ bh,
    unsigned short* __restrict__ embOut,
    float* __restrict__ outF,
    int n_nodes)
{
    __shared__ __align__(16) unsigned short A_lds[2][64][128];
    __shared__ __align__(16) unsigned short u_lds[64][128];
    __shared__ __align__(16) unsigned short wu_lds[8][32][8];

    const int t = threadIdx.x, lane = t & 63, wid = t >> 6;
    const int l15 = lane & 15, l4 = lane >> 4;
    const int wrow = wid & 3;
    const int wcolh = wid >> 2;

    bf16x8 wreg[12];
    {
        int n = wid * 16 + l15;
        #pragma unroll
        for (int kb = 0; kb < 12; ++kb)
            wreg[kb] = *reinterpret_cast<const bf16x8*>(Wbf + n * 384 + kb * 32 + l4 * 8);
    }
    #pragma unroll
    for (int kb = 0; kb < 12; ++kb)
        asm volatile("" : "+v"(wreg[kb]));

    if (wid == 0 && l4 < 2) {
        #pragma unroll
        for (int nf = 0; nf < 8; ++nf) {
            int n = nf * 16 + l15;
            bf16x8 v = {0, 0, 0, 0, 0, 0, 0, 0};
            if (l4 == 0) {
                #pragma unroll
                for (int k = 0; k < 8; ++k) ((unsigned short*)&v)[k] = f2bf(Wu[n * 8 + k]);
            } else {
                ((unsigned short*)&v)[0] = f2bf(bu[n]);
            }
            *(bf16x8*)&wu_lds[nf][l4 * 16 + l15][0] = v;
        }
    }
    const f32x4 bh4 = *(const f32x4*)&bh[wid * 16 + l4 * 4];

    bf16x8 zeroA = {0, 0, 0, 0, 0, 0, 0, 0};
    bf16x8 onesA = zeroA; ((unsigned short*)&onesA)[0] = 0x3F80;

    const int ntiles = n_nodes >> 6;
    const int stride = gridDim.x;
    const int tile0 = blockIdx.x;
    if (tile0 >= ntiles) return;

    f32x4 cO0 = {0,0,0,0}, cO1 = {0,0,0,0};

    if (!LEAF) {
        const unsigned short* src = embIn + (size_t)tile0 * 16384;
        #pragma unroll
        for (int it = 0; it < 4; ++it) {
            int q = t + it * 512;
            cp16_g2l(src + q * 8, &A_lds[0][0][0] + q * 8);
        }
    }
    if (l4 == 0) {
        const float* p = contO + ((size_t)tile0 * 64 + wrow * 16 + l15) * 8;
        cO0 = *(const f32x4*)p; cO1 = *(const f32x4*)(p + 4);
    }
    __syncthreads();

    for (int tile = tile0; tile < ntiles; tile += stride) {
        const int tnext = tile + stride;

        {
            bf16x8 cb = zeroA;
            if (l4 == 0) {
                #pragma unroll
                for (int e = 0; e < 4; ++e) {
                    ((unsigned short*)&cb)[e]     = f2bf(cO0[e]);
                    ((unsigned short*)&cb)[e + 4] = f2bf(cO1[e]);
                }
            } else if (l4 == 1) cb = onesA;
            const int i = wrow * 16 + l15;
            #pragma unroll
            for (int nfi = 0; nfi < 4; ++nfi) {
                int nf = wcolh * 4 + nfi;
                bf16x8 wv = zeroA;
                if (l4 < 2) wv = *(const bf16x8*)&wu_lds[nf][l4 * 16 + l15][0];
                f32x4 z = {0.f, 0.f, 0.f, 0.f};
                z = __builtin_amdgcn_mfma_f32_16x16x32_bf16(wv, cb, z, 0, 0, 0);
                u16x4 pk;
                #pragma unroll
                for (int r = 0; r < 4; ++r) pk[r] = f2bf(fmaxf(z[r], 0.f));
                int n4 = nf * 16 + l4 * 4;
                *(u16x4*)&u_lds[i][n4 ^ ((i & 15) << 3)] = pk;
            }
        }
        if (LEAF) {
            const float* pcBase = contC + ((size_t)tile * 128 + wrow * 32 + l15) * 8;
            #pragma unroll
            for (int rb = 0; rb < 2; ++rb) {
                bf16x8 cb = zeroA;
                if (l4 == 0) {
                    f32x4 a  = *(const f32x4*)(pcBase + rb * 128);
                    f32x4 b2 = *(const f32x4*)(pcBase + rb * 128 + 4);
                    #pragma unroll
                    for (int e = 0; e < 4; ++e) {
                        ((unsigned short*)&cb)[e]     = f2bf(a[e]);
                        ((unsigned short*)&cb)[e + 4] = f2bf(b2[e]);
                    }
                } else if (l4 == 1) cb = onesA;
                const int rr = wrow * 32 + rb * 16 + l15;
                const int cc = rr & 1, il = rr >> 1;
                #pragma unroll
                for (int nfi = 0; nfi < 4; ++nfi) {
                    int nf = wcolh * 4 + nfi;
                    bf16x8 wv = zeroA;
                    if (l4 < 2) wv = *(const bf16x8*)&wu_lds[nf][l4 * 16 + l15][0];
                    f32x4 z = {0.f, 0.f, 0.f, 0.f};
                    z = __builtin_amdgcn_mfma_f32_16x16x32_bf16(wv, cb, z, 0, 0, 0);
                    u16x4 pk;
                    #pragma unroll
                    for (int r = 0; r < 4; ++r) pk[r] = f2bf(fmaxf(z[r], 0.f));
                    int n4 = nf * 16 + l4 * 4;
                    *(u16x4*)&A_lds[cc][il][n4 ^ ((il & 15) << 3)] = pk;
                }
            }
        }

        {
            int tn = (tnext < ntiles) ? tnext : tile;
            if (l4 == 0) {
                const float* p = contO + ((size_t)tn * 64 + wrow * 16 + l15) * 8;
                cO0 = *(const f32x4*)p; cO1 = *(const f32x4*)(p + 4);
            }
        }

        if (!LEAF) asm volatile("s_waitcnt vmcnt(6)" ::: "memory");
        asm volatile("s_waitcnt lgkmcnt(0)" ::: "memory");
        __builtin_amdgcn_sched_barrier(0);
        __builtin_amdgcn_s_barrier();
        __builtin_amdgcn_sched_barrier(0);

        f32x4 acc[4];
        #pragma unroll
        for (int mf = 0; mf < 4; ++mf) acc[mf] = bh4;

        #pragma unroll
        for (int kb = 0; kb < 8; ++kb) {
            bf16x8 af[4];
            #pragma unroll
            for (int mf = 0; mf < 4; ++mf) {
                int i = mf * 16 + l15;
                af[mf] = *(const bf16x8*)&A_lds[kb >> 2][i][((((kb & 3) * 4) + l4) ^ (i & 15)) * 8];
            }
            #pragma unroll
            for (int mf = 0; mf < 4; ++mf)
                acc[mf] = __builtin_amdgcn_mfma_f32_16x16x32_bf16(wreg[kb], af[mf], acc[mf], 0, 0, 0);
        }

        if (!LEAF) {
            asm volatile("s_waitcnt lgkmcnt(0)" ::: "memory");
            __builtin_amdgcn_sched_barrier(0);
            __builtin_amdgcn_s_barrier();
            __builtin_amdgcn_sched_barrier(0);
            if (tnext < ntiles) {
                const unsigned short* src = embIn + (size_t)tnext * 16384;
                #pragma unroll
                for (int it = 0; it < 4; ++it) {
                    int q = t + it * 512;
                    cp16_g2l(src + q * 8, &A_lds[0][0][0] + q * 8);
                }
            }
        }

        #pragma unroll
        for (int kb = 8; kb < 12; ++kb) {
            bf16x8 af[4];
            #pragma unroll
            for (int mf = 0; mf < 4; ++mf) {
                int i = mf * 16 + l15;
                af[mf] = *(const bf16x8*)&u_lds[i][((((kb - 8) * 4) + l4) ^ (i & 15)) * 8];
            }
            #pragma unroll
            for (int mf = 0; mf < 4; ++mf)
                acc[mf] = __builtin_amdgcn_mfma_f32_16x16x32_bf16(wreg[kb], af[mf], acc[mf], 0, 0, 0);
        }

        if (LAST) {
            #pragma unroll
            for (int mf = 0; mf < 4; ++mf) {
                int i = mf * 16 + l15;
                f32x4 o;
                #pragma unroll
                for (int r = 0; r < 4; ++r) o[r] = fmaxf(acc[mf][r], 0.f);
                *(f32x4*)&outF[(size_t)(tile * 64 + i) * 128 + wid * 16 + l4 * 4] = o;
            }
        } else {
            #pragma unroll
            for (int mf = 0; mf < 4; ++mf) {
                int i = mf * 16 + l15;
                int Rg = tile * 64 + i;
                int rr = Rg & 127, cc = rr & 1, il = rr >> 1;
                u16x4 pk;
                #pragma unroll
                for (int r = 0; r < 4; ++r) pk[r] = f2bf(fmaxf(acc[mf][r], 0.f));
                int n4 = wid * 16 + l4 * 4;
                *(u16x4*)&embOut[(size_t)(Rg >> 7) * 16384 + cc * 8192 + il * 128
                                 + (n4 ^ ((il & 15) << 3))] = pk;
            }
        }

        asm volatile("s_waitcnt lgkmcnt(0)" ::: "memory");
        __builtin_amdgcn_sched_barrier(0);
        __builtin_amdgcn_s_barrier();
    }
}

// ================= fused tail kernel (levels 5..0) =================
// 512 blocks; block b owns rows [b*R_j, (b+1)*R_j), R_j = 2<<j (64..2).
// Children of that slice = the block's OWN previous-level output -> no
// inter-block deps. Each level writes a DISJOINT region of tbase (buffer
// reuse across levels would create a cross-block race — round-8 lesson).
// A staged via reg copy with swizzle correction (global-il vs local-il &15).
__global__ __launch_bounds__(512, 4) void k_tail(
    const float* __restrict__ c0, const float* __restrict__ c1,
    const float* __restrict__ c2, const float* __restrict__ c3,
    const float* __restrict__ c4, const float* __restrict__ c5,
    const unsigned short* __restrict__ emb6,   // from the level-6 dispatch
    const unsigned short* __restrict__ Wbf,
    const float* __restrict__ Wu, const float* __restrict__ bu,
    const float* __restrict__ bh,
    unsigned short* __restrict__ tbase,        // 15 MB of per-level regions
    float* __restrict__ outF)
{
    __shared__ __align__(16) unsigned short A_lds[2][64][128];
    __shared__ __align__(16) unsigned short u_lds[64][128];
    __shared__ __align__(16) unsigned short wu_lds[8][32][8];

    const int t = threadIdx.x, lane = t & 63, wid = t >> 6;
    const int l15 = lane & 15, l4 = lane >> 4;
    const int wrow = wid & 3;
    const int wcolh = wid >> 2;

    bf16x8 wreg[12];
    {
        int n = wid * 16 + l15;
        #pragma unroll
        for (int kb = 0; kb < 12; ++kb)
            wreg[kb] = *reinterpret_cast<const bf16x8*>(Wbf + n * 384 + kb * 32 + l4 * 8);
    }
    #pragma unroll
    for (int kb = 0; kb < 12; ++kb)
        asm volatile("" : "+v"(wreg[kb]));

    if (wid == 0 && l4 < 2) {
        #pragma unroll
        for (int nf = 0; nf < 8; ++nf) {
            int n = nf * 16 + l15;
            bf16x8 v = {0, 0, 0, 0, 0, 0, 0, 0};
            if (l4 == 0) {
                #pragma unroll
                for (int k = 0; k < 8; ++k) ((unsigned short*)&v)[k] = f2bf(Wu[n * 8 + k]);
            } else {
                ((unsigned short*)&v)[0] = f2bf(bu[n]);
            }
            *(bf16x8*)&wu_lds[nf][l4 * 16 + l15][0] = v;
        }
    }
    const f32x4 bh4 = *(const f32x4*)&bh[wid * 16 + l4 * 4];

    bf16x8 zeroA = {0, 0, 0, 0, 0, 0, 0, 0};
    bf16x8 onesA = zeroA; ((unsigned short*)&onesA)[0] = 0x3F80;

    __syncthreads();  // wu_lds visible

    const unsigned short* eIn = emb6;
    size_t accum = 0;

    for (int j = 5; j >= 0; --j) {
        const int R = 2 << j;                     // rows/block
        const float* contO = (j == 5) ? c5 : (j == 4) ? c4 : (j == 3) ? c3
                           : (j == 2) ? c2 : (j == 1) ? c1 : c0;
        unsigned short* eOut = nullptr;
        if (j > 0) { eOut = tbase + accum; accum += (size_t)(1024 << j) * 128; }

        const size_t rowBase  = (size_t)blockIdx.x * (size_t)R;
        const size_t crowBase = rowBase * 2;

        // ---- A-stage: reg copy of 2R child rows, swizzle-corrected ----
        {
            const int ilBase = ((int)(crowBase & 127)) >> 1;
            const unsigned short* gb = eIn + (crowBase >> 7) * (size_t)16384
                                     + (size_t)ilBase * 128;
            const int per = R * 16;
            for (int q = t; q < 2 * per; q += 512) {
                int cc = (q >= per) ? 1 : 0;
                int qq = q - cc * per;
                int il = qq >> 4, slot = qq & 15;
                int kc  = slot ^ (il & 15);               // logical k-chunk at dest
                int src = kc ^ ((ilBase + il) & 15);      // where producer put it
                bf16x8 v = *(const bf16x8*)(gb + (size_t)cc * 8192 + il * 128 + src * 8);
                *(bf16x8*)&A_lds[cc][il][slot * 8] = v;
            }
        }

        // ---- contents + u-phase (clamped rows; dup content for rows >= R) ----
        {
            f32x4 a0 = {0,0,0,0}, a1 = {0,0,0,0};
            if (l4 == 0) {
                size_t row = rowBase + (size_t)(wrow * 16 + l15);
                size_t mx = rowBase + R - 1; if (row > mx) row = mx;
                const float* p = contO + row * 8;
                a0 = *(const f32x4*)p; a1 = *(const f32x4*)(p + 4);
            }
            bf16x8 cb = zeroA;
            if (l4 == 0) {
                #pragma unroll
                for (int e = 0; e < 4; ++e) {
                    ((unsigned short*)&cb)[e]     = f2bf(a0[e]);
                    ((unsigned short*)&cb)[e + 4] = f2bf(a1[e]);
                }
            } else if (l4 == 1) cb = onesA;
            const int i = wrow * 16 + l15;
            #pragma unroll
            for (int nfi = 0; nfi < 4; ++nfi) {
                int nf = wcolh * 4 + nfi;
                bf16x8 wv = zeroA;
                if (l4 < 2) wv = *(const bf16x8*)&wu_lds[nf][l4 * 16 + l15][0];
                f32x4 z = {0.f, 0.f, 0.f, 0.f};
                z = __builtin_amdgcn_mfma_f32_16x16x32_bf16(wv, cb, z, 0, 0, 0);
                u16x4 pk;
                #pragma unroll
                for (int r = 0; r < 4; ++r) pk[r] = f2bf(fmaxf(z[r], 0.f));
                int n4 = nf * 16 + l4 * 4;
                *(u16x4*)&u_lds[i][n4 ^ ((i & 15) << 3)] = pk;
            }
        }

        asm volatile("s_waitcnt lgkmcnt(0)" ::: "memory");
        __builtin_amdgcn_sched_barrier(0);
        __builtin_amdgcn_s_barrier();
        __builtin_amdgcn_sched_barrier(0);

        // ---- main GEMM (rows >= R are garbage -> masked at store) ----
        f32x4 acc[4];
        #pragma unroll
        for (int mf = 0; mf < 4; ++mf) acc[mf] = bh4;

        #pragma unroll
        for (int kb = 0; kb < 8; ++kb) {
            bf16x8 af[4];
            #pragma unroll
            for (int mf = 0; mf < 4; ++mf) {
                int i = mf * 16 + l15;
                af[mf] = *(const bf16x8*)&A_lds[kb >> 2][i][((((kb & 3) * 4) + l4) ^ (i & 15)) * 8];
            }
            #pragma unroll
            for (int mf = 0; mf < 4; ++mf)
                acc[mf] = __builtin_amdgcn_mfma_f32_16x16x32_bf16(wreg[kb], af[mf], acc[mf], 0, 0, 0);
        }
        #pragma unroll
        for (int kb = 8; kb < 12; ++kb) {
            bf16x8 af[4];
            #pragma unroll
            for (int mf = 0; mf < 4; ++mf) {
                int i = mf * 16 + l15;
                af[mf] = *(const bf16x8*)&u_lds[i][((((kb - 8) * 4) + l4) ^ (i & 15)) * 8];
            }
            #pragma unroll
            for (int mf = 0; mf < 4; ++mf)
                acc[mf] = __builtin_amdgcn_mfma_f32_16x16x32_bf16(wreg[kb], af[mf], acc[mf], 0, 0, 0);
        }

        // ---- epilogue (masked i < R) ----
        if (j == 0) {
            #pragma unroll
            for (int mf = 0; mf < 4; ++mf) {
                int i = mf * 16 + l15;
                if (i < R) {
                    f32x4 o;
                    #pragma unroll
                    for (int r = 0; r < 4; ++r) o[r] = fmaxf(acc[mf][r], 0.f);
                    *(f32x4*)&outF[(rowBase + i) * 128 + wid * 16 + l4 * 4] = o;
                }
            }
        } else {
            #pragma unroll
            for (int mf = 0; mf < 4; ++mf) {
                int i = mf * 16 + l15;
                if (i < R) {
                    size_t Rg = rowBase + i;
                    int rr = (int)(Rg & 127), cc = rr & 1, il = rr >> 1;
                    u16x4 pk;
                    #pragma unroll
                    for (int r = 0; r < 4; ++r) pk[r] = f2bf(fmaxf(acc[mf][r], 0.f));
                    int n4 = wid * 16 + l4 * 4;
                    *(u16x4*)&eOut[(Rg >> 7) * 16384 + cc * 8192 + il * 128
                                   + (n4 ^ ((il & 15) << 3))] = pk;
                }
            }
        }

        // ---- level end: stores visible + LDS reads done before next level ----
        asm volatile("s_waitcnt vmcnt(0) lgkmcnt(0)" ::: "memory");
        __builtin_amdgcn_sched_barrier(0);
        __builtin_amdgcn_s_barrier();

        eIn = eOut;
    }
}

extern "C" void kernel_launch(void* const* d_in, const int* in_sizes, int n_in,
                              void* d_out, int out_size, void* d_ws, size_t ws_size,
                              hipStream_t stream) {
    const float* contents[10];
    for (int j = 0; j < 10; ++j) contents[j] = (const float*)d_in[j];
    const float* Wu = (const float*)d_in[19];
    const float* bu = (const float*)d_in[20];
    const float* Wh = (const float*)d_in[21];
    const float* bh = (const float*)d_in[22];

    unsigned short* Wbf   = (unsigned short*)d_ws;                                      // 96 KiB (1 MiB pad)
    unsigned short* bufE  = (unsigned short*)((char*)d_ws + (1u << 20));                // 64 MiB
    unsigned short* bufO  = (unsigned short*)((char*)d_ws + (1u << 20) + (64u << 20));  // 32 MiB
    unsigned short* tbase = (unsigned short*)((char*)d_ws + (1u << 20) + (96u << 20));  // 15 MiB tail regions

    k_cvtW<<<128, 384, 0, stream>>>(Wh, Wbf);

    // level 8 (leaf-fused) -> bufE
    k_level<1, 0><<<512, 512, 0, stream>>>(nullptr, contents[8], contents[9], Wbf,
                                           Wu, bu, bh, bufE, nullptr, 1024 << 8);
    // level 7: bufE -> bufO
    k_level<0, 0><<<512, 512, 0, stream>>>(bufE, contents[7], nullptr, Wbf,
                                           Wu, bu, bh, bufO, nullptr, 1024 << 7);
    // level 6: bufO -> bufE
    k_level<0, 0><<<512, 512, 0, stream>>>(bufO, contents[6], nullptr, Wbf,
                                           Wu, bu, bh, bufE, nullptr, 1024 << 6);
    // levels 5..0 fused (block-ownership, disjoint per-level regions)
    k_tail<<<512, 512, 0, stream>>>(contents[0], contents[1], contents[2], contents[3],
                                    contents[4], contents[5], bufE, Wbf,
                                    Wu, bu, bh, tbase, (float*)d_out);
}

// Round 17
// 124.537 us; speedup vs baseline: 1.9818x; 1.1605x over previous
//
#include <hip/hip_runtime.h>
#include <hip/hip_bf16.h>

typedef __attribute__((ext_vector_type(8))) short bf16x8;
typedef __attribute__((ext_vector_type(4))) float f32x4;
typedef __attribute__((ext_vector_type(4))) unsigned short u16x4;

__device__ __forceinline__ unsigned short f2bf(float f) {
    __hip_bfloat16 h = __float2bfloat16(f);   // RTNE; pairs fuse to v_cvt_pk_bf16_f32
    union { __hip_bfloat16 h; unsigned short u; } v; v.h = h;
    return v.u;
}

__device__ __forceinline__ void cp16_g2l(const void* g, void* l) {
    __builtin_amdgcn_global_load_lds(
        (const __attribute__((address_space(1))) unsigned int*)g,
        (__attribute__((address_space(3))) unsigned int*)l, 16, 0, 0);
}

// ---- one-time: W_h f32 [128][384] -> plain bf16 row-major image in ws ----
__global__ __launch_bounds__(384) void k_cvtW(const float* __restrict__ Wh,
                                              unsigned short* __restrict__ Wbf) {
    int n = blockIdx.x, k = threadIdx.x;
    Wbf[n * 384 + k] = f2bf(Wh[n * 384 + k]);
}

// =====================================================================
// Whole-tree kernel. 512 blocks; block b owns rows [b*R_j,(b+1)*R_j) at
// every level (R_j = 2<<j). Children of that slice are the block's OWN
// previous-level output -> no inter-block deps; levels separated by
// intra-block vmcnt(0)+barrier. Each level writes a DISJOINT ws region
// (offset 131072*(512-(2<<j)) elems). Tiles are block-contiguous
// (tile = b*T + tt) — ownership, NOT grid-stride.
// Inner bodies byte-identical to validated r15 k_level / r16 k_tail:
// transposed compute (thread owns 4 consecutive cols -> 8B writes),
// full-width &15 XOR swizzle, counted vmcnt(6) A-DMA pipeline.
// =====================================================================
__global__ __launch_bounds__(512, 4) void k_main(
    const float* __restrict__ c0, const float* __restrict__ c1,
    const float* __restrict__ c2, const float* __restrict__ c3,
    const float* __restrict__ c4, const float* __restrict__ c5,
    const float* __restrict__ c6, const float* __restrict__ c7,
    const float* __restrict__ c8, const float* __restrict__ c9,
    const unsigned short* __restrict__ Wbf,
    const float* __restrict__ Wu, const float* __restrict__ bu,
    const float* __restrict__ bh,
    unsigned short* __restrict__ tbase,   // 127.5 MB of per-level regions
    float* __restrict__ outF)
{
    __shared__ __align__(16) unsigned short A_lds[2][64][128]; // [cc][il][n^swz16]
    __shared__ __align__(16) unsigned short u_lds[64][128];    // [i][n^swz16]
    __shared__ __align__(16) unsigned short wu_lds[8][32][8];

    const int t = threadIdx.x, lane = t & 63, wid = t >> 6;    // 8 waves
    const int l15 = lane & 15, l4 = lane >> 4;
    const int wrow = wid & 3;
    const int wcolh = wid >> 2;
    const int b = blockIdx.x;

    // ---- persistent W fragments: wave's 16-col slice (48 VGPR, pinned) ----
    bf16x8 wreg[12];
    {
        int n = wid * 16 + l15;
        #pragma unroll
        for (int kb = 0; kb < 12; ++kb)
            wreg[kb] = *reinterpret_cast<const bf16x8*>(Wbf + n * 384 + kb * 32 + l4 * 8);
    }
    #pragma unroll
    for (int kb = 0; kb < 12; ++kb)
        asm volatile("" : "+v"(wreg[kb]));

    if (wid == 0 && l4 < 2) {
        #pragma unroll
        for (int nf = 0; nf < 8; ++nf) {
            int n = nf * 16 + l15;
            bf16x8 v = {0, 0, 0, 0, 0, 0, 0, 0};
            if (l4 == 0) {
                #pragma unroll
                for (int k = 0; k < 8; ++k) ((unsigned short*)&v)[k] = f2bf(Wu[n * 8 + k]);
            } else {
                ((unsigned short*)&v)[0] = f2bf(bu[n]);
            }
            *(bf16x8*)&wu_lds[nf][l4 * 16 + l15][0] = v;
        }
    }
    const f32x4 bh4 = *(const f32x4*)&bh[wid * 16 + l4 * 4];

    bf16x8 zeroA = {0, 0, 0, 0, 0, 0, 0, 0};
    bf16x8 onesA = zeroA; ((unsigned short*)&onesA)[0] = 0x3F80;

    __syncthreads();  // wu_lds visible

    // region pointer for level j's emb output
    #define RG(j) (tbase + (size_t)131072 * (512 - (2 << (j))))

    f32x4 cO0 = {0,0,0,0}, cO1 = {0,0,0,0};

    // ================= LEVEL 8 (leaf): T=8 full tiles =================
    {
        const int T = 8;
        const int tb = b * T;
        unsigned short* eOut = RG(8);
        if (l4 == 0) {
            const float* p = c8 + ((size_t)tb * 64 + wrow * 16 + l15) * 8;
            cO0 = *(const f32x4*)p; cO1 = *(const f32x4*)(p + 4);
        }
        for (int tt = 0; tt < T; ++tt) {
            const int tile = tb + tt;
            // ---- u-phase ----
            {
                bf16x8 cb = zeroA;
                if (l4 == 0) {
                    #pragma unroll
                    for (int e = 0; e < 4; ++e) {
                        ((unsigned short*)&cb)[e]     = f2bf(cO0[e]);
                        ((unsigned short*)&cb)[e + 4] = f2bf(cO1[e]);
                    }
                } else if (l4 == 1) cb = onesA;
                const int i = wrow * 16 + l15;
                #pragma unroll
                for (int nfi = 0; nfi < 4; ++nfi) {
                    int nf = wcolh * 4 + nfi;
                    bf16x8 wv = zeroA;
                    if (l4 < 2) wv = *(const bf16x8*)&wu_lds[nf][l4 * 16 + l15][0];
                    f32x4 z = {0.f, 0.f, 0.f, 0.f};
                    z = __builtin_amdgcn_mfma_f32_16x16x32_bf16(wv, cb, z, 0, 0, 0);
                    u16x4 pk;
                    #pragma unroll
                    for (int r = 0; r < 4; ++r) pk[r] = f2bf(fmaxf(z[r], 0.f));
                    int n4 = nf * 16 + l4 * 4;
                    *(u16x4*)&u_lds[i][n4 ^ ((i & 15) << 3)] = pk;
                }
            }
            // ---- child-u: direct loads from c9 ----
            {
                const float* pcBase = c9 + ((size_t)tile * 128 + wrow * 32 + l15) * 8;
                #pragma unroll
                for (int rb = 0; rb < 2; ++rb) {
                    bf16x8 cb = zeroA;
                    if (l4 == 0) {
                        f32x4 a  = *(const f32x4*)(pcBase + rb * 128);
                        f32x4 b2 = *(const f32x4*)(pcBase + rb * 128 + 4);
                        #pragma unroll
                        for (int e = 0; e < 4; ++e) {
                            ((unsigned short*)&cb)[e]     = f2bf(a[e]);
                            ((unsigned short*)&cb)[e + 4] = f2bf(b2[e]);
                        }
                    } else if (l4 == 1) cb = onesA;
                    const int rr = wrow * 32 + rb * 16 + l15;
                    const int cc = rr & 1, il = rr >> 1;
                    #pragma unroll
                    for (int nfi = 0; nfi < 4; ++nfi) {
                        int nf = wcolh * 4 + nfi;
                        bf16x8 wv = zeroA;
                        if (l4 < 2) wv = *(const bf16x8*)&wu_lds[nf][l4 * 16 + l15][0];
                        f32x4 z = {0.f, 0.f, 0.f, 0.f};
                        z = __builtin_amdgcn_mfma_f32_16x16x32_bf16(wv, cb, z, 0, 0, 0);
                        u16x4 pk;
                        #pragma unroll
                        for (int r = 0; r < 4; ++r) pk[r] = f2bf(fmaxf(z[r], 0.f));
                        int n4 = nf * 16 + l4 * 4;
                        *(u16x4*)&A_lds[cc][il][n4 ^ ((il & 15) << 3)] = pk;
                    }
                }
            }
            // ---- prefetch next tile's contents (clamped) ----
            {
                int tn = (tt + 1 < T) ? tile + 1 : tile;
                if (l4 == 0) {
                    const float* p = c8 + ((size_t)tn * 64 + wrow * 16 + l15) * 8;
                    cO0 = *(const f32x4*)p; cO1 = *(const f32x4*)(p + 4);
                }
            }
            asm volatile("s_waitcnt lgkmcnt(0)" ::: "memory");
            __builtin_amdgcn_sched_barrier(0);
            __builtin_amdgcn_s_barrier();
            __builtin_amdgcn_sched_barrier(0);

            f32x4 acc[4];
            #pragma unroll
            for (int mf = 0; mf < 4; ++mf) acc[mf] = bh4;
            #pragma unroll
            for (int kb = 0; kb < 8; ++kb) {
                bf16x8 af[4];
                #pragma unroll
                for (int mf = 0; mf < 4; ++mf) {
                    int i = mf * 16 + l15;
                    af[mf] = *(const bf16x8*)&A_lds[kb >> 2][i][((((kb & 3) * 4) + l4) ^ (i & 15)) * 8];
                }
                #pragma unroll
                for (int mf = 0; mf < 4; ++mf)
                    acc[mf] = __builtin_amdgcn_mfma_f32_16x16x32_bf16(wreg[kb], af[mf], acc[mf], 0, 0, 0);
            }
            #pragma unroll
            for (int kb = 8; kb < 12; ++kb) {
                bf16x8 af[4];
                #pragma unroll
                for (int mf = 0; mf < 4; ++mf) {
                    int i = mf * 16 + l15;
                    af[mf] = *(const bf16x8*)&u_lds[i][((((kb - 8) * 4) + l4) ^ (i & 15)) * 8];
                }
                #pragma unroll
                for (int mf = 0; mf < 4; ++mf)
                    acc[mf] = __builtin_amdgcn_mfma_f32_16x16x32_bf16(wreg[kb], af[mf], acc[mf], 0, 0, 0);
            }
            #pragma unroll
            for (int mf = 0; mf < 4; ++mf) {
                int i = mf * 16 + l15;
                int Rg = tile * 64 + i;
                int rr = Rg & 127, cc = rr & 1, il = rr >> 1;
                u16x4 pk;
                #pragma unroll
                for (int r = 0; r < 4; ++r) pk[r] = f2bf(fmaxf(acc[mf][r], 0.f));
                int n4 = wid * 16 + l4 * 4;
                *(u16x4*)&eOut[(size_t)(Rg >> 7) * 16384 + cc * 8192 + il * 128
                               + (n4 ^ ((il & 15) << 3))] = pk;
            }
            asm volatile("s_waitcnt lgkmcnt(0)" ::: "memory");
            __builtin_amdgcn_sched_barrier(0);
            __builtin_amdgcn_s_barrier();
        }
        // level end: stores visible before next level's DMA reads
        asm volatile("s_waitcnt vmcnt(0) lgkmcnt(0)" ::: "memory");
        __builtin_amdgcn_sched_barrier(0);
        __builtin_amdgcn_s_barrier();
    }

    // ================= LEVELS 7..5: full-tile DMA levels =================
    for (int j = 7; j >= 5; --j) {
        const int T = 1 << (j - 5);     // 4, 2, 1
        const int tb = b * T;
        const float* contO = (j == 7) ? c7 : (j == 6) ? c6 : c5;
        const unsigned short* eIn = RG(j + 1);
        unsigned short* eOut = RG(j);

        // prologue: tile0 DMA + contents, full drain
        {
            const unsigned short* src = eIn + (size_t)tb * 16384;
            #pragma unroll
            for (int it = 0; it < 4; ++it) {
                int q = t + it * 512;
                cp16_g2l(src + q * 8, &A_lds[0][0][0] + q * 8);
            }
            if (l4 == 0) {
                const float* p = contO + ((size_t)tb * 64 + wrow * 16 + l15) * 8;
                cO0 = *(const f32x4*)p; cO1 = *(const f32x4*)(p + 4);
            }
        }
        __syncthreads();

        for (int tt = 0; tt < T; ++tt) {
            const int tile = tb + tt;
            // ---- u-phase ----
            {
                bf16x8 cb = zeroA;
                if (l4 == 0) {
                    #pragma unroll
                    for (int e = 0; e < 4; ++e) {
                        ((unsigned short*)&cb)[e]     = f2bf(cO0[e]);
                        ((unsigned short*)&cb)[e + 4] = f2bf(cO1[e]);
                    }
                } else if (l4 == 1) cb = onesA;
                const int i = wrow * 16 + l15;
                #pragma unroll
                for (int nfi = 0; nfi < 4; ++nfi) {
                    int nf = wcolh * 4 + nfi;
                    bf16x8 wv = zeroA;
                    if (l4 < 2) wv = *(const bf16x8*)&wu_lds[nf][l4 * 16 + l15][0];
                    f32x4 z = {0.f, 0.f, 0.f, 0.f};
                    z = __builtin_amdgcn_mfma_f32_16x16x32_bf16(wv, cb, z, 0, 0, 0);
                    u16x4 pk;
                    #pragma unroll
                    for (int r = 0; r < 4; ++r) pk[r] = f2bf(fmaxf(z[r], 0.f));
                    int n4 = nf * 16 + l4 * 4;
                    *(u16x4*)&u_lds[i][n4 ^ ((i & 15) << 3)] = pk;
                }
            }
            // ---- prefetch next tile's contents (clamped) ----
            {
                int tn = (tt + 1 < T) ? tile + 1 : tile;
                if (l4 == 0) {
                    const float* p = contO + ((size_t)tn * 64 + wrow * 16 + l15) * 8;
                    cO0 = *(const f32x4*)p; cO1 = *(const f32x4*)(p + 4);
                }
            }
            asm volatile("s_waitcnt vmcnt(6)" ::: "memory");  // drain 4 DMA; leave 4 stores + 2 loads
            asm volatile("s_waitcnt lgkmcnt(0)" ::: "memory");
            __builtin_amdgcn_sched_barrier(0);
            __builtin_amdgcn_s_barrier();
            __builtin_amdgcn_sched_barrier(0);

            f32x4 acc[4];
            #pragma unroll
            for (int mf = 0; mf < 4; ++mf) acc[mf] = bh4;
            #pragma unroll
            for (int kb = 0; kb < 8; ++kb) {
                bf16x8 af[4];
                #pragma unroll
                for (int mf = 0; mf < 4; ++mf) {
                    int i = mf * 16 + l15;
                    af[mf] = *(const bf16x8*)&A_lds[kb >> 2][i][((((kb & 3) * 4) + l4) ^ (i & 15)) * 8];
                }
                #pragma unroll
                for (int mf = 0; mf < 4; ++mf)
                    acc[mf] = __builtin_amdgcn_mfma_f32_16x16x32_bf16(wreg[kb], af[mf], acc[mf], 0, 0, 0);
            }
            // A consumed -> barrier, then prefetch next tile's A DMA
            asm volatile("s_waitcnt lgkmcnt(0)" ::: "memory");
            __builtin_amdgcn_sched_barrier(0);
            __builtin_amdgcn_s_barrier();
            __builtin_amdgcn_sched_barrier(0);
            if (tt + 1 < T) {
                const unsigned short* src = eIn + (size_t)(tile + 1) * 16384;
                #pragma unroll
                for (int it = 0; it < 4; ++it) {
                    int q = t + it * 512;
                    cp16_g2l(src + q * 8, &A_lds[0][0][0] + q * 8);
                }
            }
            #pragma unroll
            for (int kb = 8; kb < 12; ++kb) {
                bf16x8 af[4];
                #pragma unroll
                for (int mf = 0; mf < 4; ++mf) {
                    int i = mf * 16 + l15;
                    af[mf] = *(const bf16x8*)&u_lds[i][((((kb - 8) * 4) + l4) ^ (i & 15)) * 8];
                }
                #pragma unroll
                for (int mf = 0; mf < 4; ++mf)
                    acc[mf] = __builtin_amdgcn_mfma_f32_16x16x32_bf16(wreg[kb], af[mf], acc[mf], 0, 0, 0);
            }
            #pragma unroll
            for (int mf = 0; mf < 4; ++mf) {
                int i = mf * 16 + l15;
                int Rg = tile * 64 + i;
                int rr = Rg & 127, cc = rr & 1, il = rr >> 1;
                u16x4 pk;
                #pragma unroll
                for (int r = 0; r < 4; ++r) pk[r] = f2bf(fmaxf(acc[mf][r], 0.f));
                int n4 = wid * 16 + l4 * 4;
                *(u16x4*)&eOut[(size_t)(Rg >> 7) * 16384 + cc * 8192 + il * 128
                               + (n4 ^ ((il & 15) << 3))] = pk;
            }
            asm volatile("s_waitcnt lgkmcnt(0)" ::: "memory");
            __builtin_amdgcn_sched_barrier(0);
            __builtin_amdgcn_s_barrier();
        }
        asm volatile("s_waitcnt vmcnt(0) lgkmcnt(0)" ::: "memory");
        __builtin_amdgcn_sched_barrier(0);
        __builtin_amdgcn_s_barrier();
    }

    // ================= LEVELS 4..0: partial (reg-staged) =================
    for (int j = 4; j >= 0; --j) {
        const int R = 2 << j;            // 32..2
        const float* contO = (j == 4) ? c4 : (j == 3) ? c3 : (j == 2) ? c2
                           : (j == 1) ? c1 : c0;
        const unsigned short* eIn = RG(j + 1);
        unsigned short* eOut = (j > 0) ? RG(j) : nullptr;

        const size_t rowBase  = (size_t)b * (size_t)R;
        const size_t crowBase = rowBase * 2;

        // A-stage: reg copy of 2R child rows, swizzle-corrected
        {
            const int ilBase = ((int)(crowBase & 127)) >> 1;
            const unsigned short* gb = eIn + (crowBase >> 7) * (size_t)16384
                                     + (size_t)ilBase * 128;
            const int per = R * 16;
            for (int q = t; q < 2 * per; q += 512) {
                int cc = (q >= per) ? 1 : 0;
                int qq = q - cc * per;
                int il = qq >> 4, slot = qq & 15;
                int kc  = slot ^ (il & 15);
                int src = kc ^ ((ilBase + il) & 15);
                bf16x8 v = *(const bf16x8*)(gb + (size_t)cc * 8192 + il * 128 + src * 8);
                *(bf16x8*)&A_lds[cc][il][slot * 8] = v;
            }
        }
        // contents + u-phase (clamped rows)
        {
            f32x4 a0 = {0,0,0,0}, a1 = {0,0,0,0};
            if (l4 == 0) {
                size_t row = rowBase + (size_t)(wrow * 16 + l15);
                size_t mx = rowBase + R - 1; if (row > mx) row = mx;
                const float* p = contO + row * 8;
                a0 = *(const f32x4*)p; a1 = *(const f32x4*)(p + 4);
            }
            bf16x8 cb = zeroA;
            if (l4 == 0) {
                #pragma unroll
                for (int e = 0; e < 4; ++e) {
                    ((unsigned short*)&cb)[e]     = f2bf(a0[e]);
                    ((unsigned short*)&cb)[e + 4] = f2bf(a1[e]);
                }
            } else if (l4 == 1) cb = onesA;
            const int i = wrow * 16 + l15;
            #pragma unroll
            for (int nfi = 0; nfi < 4; ++nfi) {
                int nf = wcolh * 4 + nfi;
                bf16x8 wv = zeroA;
                if (l4 < 2) wv = *(const bf16x8*)&wu_lds[nf][l4 * 16 + l15][0];
                f32x4 z = {0.f, 0.f, 0.f, 0.f};
                z = __builtin_amdgcn_mfma_f32_16x16x32_bf16(wv, cb, z, 0, 0, 0);
                u16x4 pk;
                #pragma unroll
                for (int r = 0; r < 4; ++r) pk[r] = f2bf(fmaxf(z[r], 0.f));
                int n4 = nf * 16 + l4 * 4;
                *(u16x4*)&u_lds[i][n4 ^ ((i & 15) << 3)] = pk;
            }
        }
        asm volatile("s_waitcnt lgkmcnt(0)" ::: "memory");
        __builtin_amdgcn_sched_barrier(0);
        __builtin_amdgcn_s_barrier();
        __builtin_amdgcn_sched_barrier(0);

        f32x4 acc[4];
        #pragma unroll
        for (int mf = 0; mf < 4; ++mf) acc[mf] = bh4;
        #pragma unroll
        for (int kb = 0; kb < 8; ++kb) {
            bf16x8 af[4];
            #pragma unroll
            for (int mf = 0; mf < 4; ++mf) {
                int i = mf * 16 + l15;
                af[mf] = *(const bf16x8*)&A_lds[kb >> 2][i][((((kb & 3) * 4) + l4) ^ (i & 15)) * 8];
            }
            #pragma unroll
            for (int mf = 0; mf < 4; ++mf)
                acc[mf] = __builtin_amdgcn_mfma_f32_16x16x32_bf16(wreg[kb], af[mf], acc[mf], 0, 0, 0);
        }
        #pragma unroll
        for (int kb = 8; kb < 12; ++kb) {
            bf16x8 af[4];
            #pragma unroll
            for (int mf = 0; mf < 4; ++mf) {
                int i = mf * 16 + l15;
                af[mf] = *(const bf16x8*)&u_lds[i][((((kb - 8) * 4) + l4) ^ (i & 15)) * 8];
            }
            #pragma unroll
            for (int mf = 0; mf < 4; ++mf)
                acc[mf] = __builtin_amdgcn_mfma_f32_16x16x32_bf16(wreg[kb], af[mf], acc[mf], 0, 0, 0);
        }
        if (j == 0) {
            #pragma unroll
            for (int mf = 0; mf < 4; ++mf) {
                int i = mf * 16 + l15;
                if (i < R) {
                    f32x4 o;
                    #pragma unroll
                    for (int r = 0; r < 4; ++r) o[r] = fmaxf(acc[mf][r], 0.f);
                    *(f32x4*)&outF[(rowBase + i) * 128 + wid * 16 + l4 * 4] = o;
                }
            }
        } else {
            #pragma unroll
            for (int mf = 0; mf < 4; ++mf) {
                int i = mf * 16 + l15;
                if (i < R) {
                    size_t Rg = rowBase + i;
                    int rr = (int)(Rg & 127), cc = rr & 1, il = rr >> 1;
                    u16x4 pk;
                    #pragma unroll
                    for (int r = 0; r < 4; ++r) pk[r] = f2bf(fmaxf(acc[mf][r], 0.f));
                    int n4 = wid * 16 + l4 * 4;
                    *(u16x4*)&eOut[(Rg >> 7) * 16384 + cc * 8192 + il * 128
                                   + (n4 ^ ((il & 15) << 3))] = pk;
                }
            }
        }
        asm volatile("s_waitcnt vmcnt(0) lgkmcnt(0)" ::: "memory");
        __builtin_amdgcn_sched_barrier(0);
        __builtin_amdgcn_s_barrier();
    }
    #undef RG
}

extern "C" void kernel_launch(void* const* d_in, const int* in_sizes, int n_in,
                              void* d_out, int out_size, void* d_ws, size_t ws_size,
                              hipStream_t stream) {
    const float* c[10];
    for (int j = 0; j < 10; ++j) c[j] = (const float*)d_in[j];
    const float* Wu = (const float*)d_in[19];
    const float* bu = (const float*)d_in[20];
    const float* Wh = (const float*)d_in[21];
    const float* bh = (const float*)d_in[22];

    unsigned short* Wbf   = (unsigned short*)d_ws;                       // 96 KiB (1 MiB pad)
    unsigned short* tbase = (unsigned short*)((char*)d_ws + (1u << 20)); // 127.5 MiB regions

    k_cvtW<<<128, 384, 0, stream>>>(Wh, Wbf);
    k_main<<<512, 512, 0, stream>>>(c[0], c[1], c[2], c[3], c[4], c[5], c[6], c[7],
                                    c[8], c[9], Wbf, Wu, bu, bh, tbase, (float*)d_out);
}